// Round 1
// baseline (465.391 us; speedup 1.0000x reference)
//
#include <hip/hip_runtime.h>
#include <hip/hip_bf16.h>

// QuantizedSimpleSSM — round 6: LDS double-buffer in gemm_pass (one barrier per
// 16-k tile instead of two) + next-tile global loads issued BEFORE the current
// tile's compute so HBM latency hides under the 1024-FMA block (vmcnt wait lands
// at the ds_writes). FMA order per output unchanged (same tiles, ascending k) ->
// bitwise identical to R5. recur re-gridded to (32,8)x64 so all 256 CUs run a
// chain (was 128 blocks on half the chip); per-(b,n) chain bitwise unchanged.
// Numerics contract (absmax 0.0 since R2): every output element is one fp32 FMA
// chain in strictly ascending k; recurrence mul-then-add + q8.

#define DINX 512
#define LSEQ 512
#define NDIM 512

__device__ __forceinline__ float q8(float x) {
    float xa = fabsf(x);
    float w  = __fadd_rn(xa, 1e-8f);
    int e = (int)((__float_as_uint(w) >> 23) & 0xFFu) - 127;   // floor(log2(w))
    e = e < -7 ? -7 : (e > 7 ? 7 : e);
    float p    = __int_as_float((unsigned)((e + 127) << 23));   // exact 2^e
    float invp = __int_as_float((unsigned)((127 - e) << 23));   // exact 2^-e
    float t  = __fmul_rn(__fsub_rn(__fmul_rn(xa, invp), 1.0f), 8.0f);
    float m  = __fmul_rn(rintf(t), 0.125f);                     // half-to-even
    float r  = __fmul_rn(__fadd_rn(1.0f, m), p);
    return copysignf(r, x);
}

__global__ void quantk(const float* __restrict__ in, float* __restrict__ out, int n) {
    int i = blockIdx.x * blockDim.x + threadIdx.x;
    if (i < n) out[i] = q8(in[i]);
}

// out[c][r] = q8(in[r][c]) for three 512x512 matrices. grid (16,16,3), block 256.
__global__ __launch_bounds__(256) void quantT3(const float* __restrict__ B,
                                               const float* __restrict__ C,
                                               const float* __restrict__ D,
                                               float* __restrict__ Bqt,
                                               float* __restrict__ Cqt,
                                               float* __restrict__ Dqt) {
    __shared__ float tl[32][33];
    const float* in = blockIdx.z == 0 ? B : (blockIdx.z == 1 ? C : D);
    float* out      = blockIdx.z == 0 ? Bqt : (blockIdx.z == 1 ? Cqt : Dqt);
    const int r0 = blockIdx.y * 32, c0 = blockIdx.x * 32;
    const int x = threadIdx.x & 31, y = threadIdx.x >> 5;   // 32 x 8
#pragma unroll
    for (int i = 0; i < 32; i += 8)
        tl[y + i][x] = q8(in[(r0 + y + i) * 512 + c0 + x]);
    __syncthreads();
#pragma unroll
    for (int i = 0; i < 32; i += 8)
        out[(c0 + y + i) * 512 + r0 + x] = tl[x][y + i];
}

// One 16-k compute block: acc[p][i][q][j] += Xs[base+k][..]*Ws[base+k][..],
// k ascending. Fragment layout: 16-B chunks at 4-dword stride (2-way bank
// aliasing max = free; Ws reads broadcast within quarter-waves).
__device__ __forceinline__ void tile16(const float (*Xs)[128], const float (*Ws)[128],
                                       int base, int tx, int ty,
                                       float (&acc)[2][4][2][4]) {
#pragma unroll
    for (int k = 0; k < 16; ++k) {
        float a[2][4], b[2][4];
        *(float4*)&a[0][0] = *(const float4*)&Xs[base + k][tx * 4];
        *(float4*)&a[1][0] = *(const float4*)&Xs[base + k][64 + tx * 4];
        *(float4*)&b[0][0] = *(const float4*)&Ws[base + k][ty * 4];
        *(float4*)&b[1][0] = *(const float4*)&Ws[base + k][64 + ty * 4];
#pragma unroll
        for (int p = 0; p < 2; ++p)
#pragma unroll
            for (int i = 0; i < 4; ++i)
#pragma unroll
                for (int q = 0; q < 2; ++q)
#pragma unroll
                    for (int j = 0; j < 4; ++j)
                        acc[p][i][q][j] = fmaf(a[p][i], b[q][j], acc[p][i][q][j]);
    }
}

// acc[p][i][q][j] += sum_k X[k][m0 + p*64 + tx*4 + i] * W[k][n0 + q*64 + ty*4 + j],
// k strictly ascending. X, W are [KTOT][512] row-major.
// LDS: Xs/Ws [32][128] = two 16-row buffers, ping-pong. Loop structure per
// tile it: issue global loads for tile it+1 -> compute tile it (hides latency)
// -> vmcnt wait + ds_write other buffer -> ONE barrier.
__device__ __forceinline__ void gemm_pass(const float* __restrict__ X,
                                          const float* __restrict__ W,
                                          int m0, int n0, int KTOT,
                                          float (&acc)[2][4][2][4],
                                          float (*Xs)[128], float (*Ws)[128],
                                          int tid) {
    const int tx = tid & 15, ty = tid >> 4;
    const int srow = tid >> 4, sseg4 = (tid & 15) * 4;
    const float* xp = X + (size_t)srow * 512 + m0 + sseg4;
    const float* wp = W + (size_t)srow * 512 + n0 + sseg4;

    // prologue: stage tile 0 into buffer 0 (rows 0..15)
    {
        float4 x0 = *(const float4*)xp;
        float4 x1 = *(const float4*)(xp + 64);
        float4 w0 = *(const float4*)wp;
        float4 w1 = *(const float4*)(wp + 64);
        xp += 16 * 512; wp += 16 * 512;
        __syncthreads();                 // prev-pass reads done before overwrite
        *(float4*)&Xs[srow][sseg4]      = x0;
        *(float4*)&Xs[srow][64 + sseg4] = x1;
        *(float4*)&Ws[srow][sseg4]      = w0;
        *(float4*)&Ws[srow][64 + sseg4] = w1;
        __syncthreads();
    }
    const int NT = KTOT >> 4;
    for (int it = 0; it < NT - 1; ++it) {
        // issue next tile's loads first; latency hides under tile16's 1024 FMAs
        float4 nx0 = *(const float4*)xp;
        float4 nx1 = *(const float4*)(xp + 64);
        float4 nw0 = *(const float4*)wp;
        float4 nw1 = *(const float4*)(wp + 64);
        xp += 16 * 512; wp += 16 * 512;
        const int base = (it & 1) << 4;
        tile16(Xs, Ws, base, tx, ty, acc);
        const int nb = (base ^ 16) + srow;   // other buffer: safe, nobody reads
        *(float4*)&Xs[nb][sseg4]      = nx0; // it until after the barrier below
        *(float4*)&Xs[nb][64 + sseg4] = nx1;
        *(float4*)&Ws[nb][sseg4]      = nw0;
        *(float4*)&Ws[nb][64 + sseg4] = nw1;
        __syncthreads();
    }
    tile16(Xs, Ws, ((NT - 1) & 1) << 4, tx, ty, acc);
}

// R[b][t][n] = sum_d u[b][d][t] * Bqt[d][n]. grid (4,4,32), block 256.
__global__ __launch_bounds__(256) void gemm_R(const float* __restrict__ u,
                                              const float* __restrict__ Bqt,
                                              float* __restrict__ R) {
    __shared__ float Xs[32][128];
    __shared__ float Ws[32][128];
    const int b  = blockIdx.z;
    const int t0 = blockIdx.x * 128, n0 = blockIdx.y * 128;
    const int tid = threadIdx.x;
    const int tx = tid & 15, ty = tid >> 4;
    const float* ub = u + (size_t)b * (DINX * LSEQ);
    float acc[2][4][2][4] = {};
    gemm_pass(ub, Bqt, t0, n0, DINX, acc, Xs, Ws, tid);
    float* Rb = R + (size_t)b * (LSEQ * NDIM);
#pragma unroll
    for (int p = 0; p < 2; ++p)
#pragma unroll
        for (int i = 0; i < 4; ++i) {
            float* row = Rb + (size_t)(t0 + p * 64 + tx * 4 + i) * NDIM + n0;
            *(float4*)(row + ty * 4)      = make_float4(acc[p][i][0][0], acc[p][i][0][1],
                                                        acc[p][i][0][2], acc[p][i][0][3]);
            *(float4*)(row + 64 + ty * 4) = make_float4(acc[p][i][1][0], acc[p][i][1][1],
                                                        acc[p][i][1][2], acc[p][i][1][3]);
        }
}

// Per-(b, n-chunk) recurrence (bitwise np: mul-then-add, q8). Writes S[b][n][t].
// grid (32, 8), block 64 (thread = one n within a 64-wide chunk) -> 256 blocks,
// one chain-wave per CU (was 128 blocks = half the chip idle).
__global__ __launch_bounds__(64) void recur(const float* __restrict__ R,
                                            const float* __restrict__ Aq,
                                            float* __restrict__ S) {
    __shared__ float tile[16][68];
    const int b  = blockIdx.x;
    const int n0 = blockIdx.y * 64;
    const int n  = threadIdx.x;                 // 0..63
    const float a = Aq[n0 + n];
    const float* Rb = R + (size_t)b * (LSEQ * NDIM) + n0;
    float* Sb = S + (size_t)b * (NDIM * LSEQ) + (size_t)n0 * LSEQ;
    float s = 0.0f;
    const int c = (n & 3) * 4;
    const int rbase = n >> 2;                   // 0..15
    for (int t0 = 0; t0 < LSEQ; t0 += 16) {
#pragma unroll
        for (int tt = 0; tt < 16; ++tt) {
            float r = Rb[(size_t)(t0 + tt) * NDIM + n];
            s = q8(__fadd_rn(__fmul_rn(s, a), r));
            tile[tt][n] = s;
        }
        __syncthreads();
#pragma unroll
        for (int p = 0; p < 4; ++p) {
            int row = p * 16 + rbase;
            float4 v = make_float4(tile[c + 0][row], tile[c + 1][row],
                                   tile[c + 2][row], tile[c + 3][row]);
            *(float4*)(Sb + (size_t)row * LSEQ + t0 + c) = v;
        }
        __syncthreads();
    }
}

// Y[b][o][t] = q8( (sum_n S[n][t]*Cqt[n][o]) + (sum_d u[d][t]*Dqt[d][o]) )
__global__ __launch_bounds__(256) void gemm_Y(const float* __restrict__ u,
                                              const float* __restrict__ S,
                                              const float* __restrict__ Cqt,
                                              const float* __restrict__ Dqt,
                                              float* __restrict__ Y) {
    __shared__ float Xs[32][128];
    __shared__ float Ws[32][128];
    const int b  = blockIdx.z;
    const int t0 = blockIdx.x * 128, o0 = blockIdx.y * 128;
    const int tid = threadIdx.x;
    const int tx = tid & 15, ty = tid >> 4;
    const float* Sb = S + (size_t)b * (NDIM * LSEQ);
    const float* ub = u + (size_t)b * (DINX * LSEQ);
    float acc[2][4][2][4] = {};
    float c1[2][4][2][4];
    gemm_pass(Sb, Cqt, t0, o0, NDIM, acc, Xs, Ws, tid);
#pragma unroll
    for (int p = 0; p < 2; ++p)
#pragma unroll
        for (int i = 0; i < 4; ++i)
#pragma unroll
            for (int q = 0; q < 2; ++q)
#pragma unroll
                for (int j = 0; j < 4; ++j) {
                    c1[p][i][q][j] = acc[p][i][q][j];
                    acc[p][i][q][j] = 0.0f;
                }
    gemm_pass(ub, Dqt, t0, o0, DINX, acc, Xs, Ws, tid);

    float* Yb = Y + (size_t)b * (NDIM * LSEQ);
#pragma unroll
    for (int q = 0; q < 2; ++q)
#pragma unroll
        for (int j = 0; j < 4; ++j) {
            float y0[4], y1[4];
#pragma unroll
            for (int i = 0; i < 4; ++i) {
                y0[i] = q8(__fadd_rn(c1[0][i][q][j], acc[0][i][q][j]));
                y1[i] = q8(__fadd_rn(c1[1][i][q][j], acc[1][i][q][j]));
            }
            float* row = Yb + (size_t)(o0 + q * 64 + ty * 4 + j) * LSEQ + t0;
            *(float4*)(row + tx * 4)      = make_float4(y0[0], y0[1], y0[2], y0[3]);
            *(float4*)(row + 64 + tx * 4) = make_float4(y1[0], y1[1], y1[2], y1[3]);
        }
}

extern "C" void kernel_launch(void* const* d_in, const int* in_sizes, int n_in,
                              void* d_out, int out_size, void* d_ws, size_t ws_size,
                              hipStream_t stream) {
    const float* u = (const float*)d_in[0];   // (32, 512, 512)
    const float* A = (const float*)d_in[1];   // (512,)
    const float* B = (const float*)d_in[2];   // (512, 512)
    const float* C = (const float*)d_in[3];   // (512, 512)
    const float* D = (const float*)d_in[4];   // (512, 512)

    float* ws  = (float*)d_ws;
    float* Aq  = ws;                    // 512
    float* Bqt = Aq + 512;              // 262144  [d][n]
    float* Cqt = Bqt + 262144;          // 262144  [n][o]
    float* Dqt = Cqt + 262144;          // 262144  [d][o]
    float* R   = Dqt + 262144;          // 8388608 [b][t][n]
    float* S   = R + 8388608;           // 8388608 [b][n][t]
    float* Y   = (float*)d_out;         // 8388608 [b][o][t]

    quantk<<<2, 256, 0, stream>>>(A, Aq, 512);
    quantT3<<<dim3(16, 16, 3), 256, 0, stream>>>(B, C, D, Bqt, Cqt, Dqt);

    gemm_R<<<dim3(4, 4, 32), 256, 0, stream>>>(u, Bqt, R);
    recur<<<dim3(32, 8), 64, 0, stream>>>(R, Aq, S);
    gemm_Y<<<dim3(4, 4, 32), 256, 0, stream>>>(u, S, Cqt, Dqt, Y);
}

// Round 2
// 388.778 us; speedup vs baseline: 1.1971x; 1.1971x over previous
//
#include <hip/hip_runtime.h>
#include <hip/hip_bf16.h>

// QuantizedSimpleSSM — round 7: revert R6 double-buffer (VGPR hit 256 -> lost
// the 2nd co-resident block; R5's latency hiding was CROSS-BLOCK TLP, not
// intra-wave). Keep R5 single-buffer skeleton, but BK 16 -> 32: barrier pairs
// and exposed-load stalls amortize over 2048 FMAs instead of 1024. Staging regs
// ~32 float4 live across one barrier -> ~140-160 VGPR, still 2 waves/SIMD.
// Keep R6 recur re-grid ((32,8)x64 = 256 blocks, all CUs busy).
// Numerics contract (absmax 0.0 since R2): every output element is one fp32 FMA
// chain in strictly ascending k; recurrence mul-then-add + q8.

#define DINX 512
#define LSEQ 512
#define NDIM 512

__device__ __forceinline__ float q8(float x) {
    float xa = fabsf(x);
    float w  = __fadd_rn(xa, 1e-8f);
    int e = (int)((__float_as_uint(w) >> 23) & 0xFFu) - 127;   // floor(log2(w))
    e = e < -7 ? -7 : (e > 7 ? 7 : e);
    float p    = __int_as_float((unsigned)((e + 127) << 23));   // exact 2^e
    float invp = __int_as_float((unsigned)((127 - e) << 23));   // exact 2^-e
    float t  = __fmul_rn(__fsub_rn(__fmul_rn(xa, invp), 1.0f), 8.0f);
    float m  = __fmul_rn(rintf(t), 0.125f);                     // half-to-even
    float r  = __fmul_rn(__fadd_rn(1.0f, m), p);
    return copysignf(r, x);
}

__global__ void quantk(const float* __restrict__ in, float* __restrict__ out, int n) {
    int i = blockIdx.x * blockDim.x + threadIdx.x;
    if (i < n) out[i] = q8(in[i]);
}

// out[c][r] = q8(in[r][c]) for three 512x512 matrices. grid (16,16,3), block 256.
__global__ __launch_bounds__(256) void quantT3(const float* __restrict__ B,
                                               const float* __restrict__ C,
                                               const float* __restrict__ D,
                                               float* __restrict__ Bqt,
                                               float* __restrict__ Cqt,
                                               float* __restrict__ Dqt) {
    __shared__ float tl[32][33];
    const float* in = blockIdx.z == 0 ? B : (blockIdx.z == 1 ? C : D);
    float* out      = blockIdx.z == 0 ? Bqt : (blockIdx.z == 1 ? Cqt : Dqt);
    const int r0 = blockIdx.y * 32, c0 = blockIdx.x * 32;
    const int x = threadIdx.x & 31, y = threadIdx.x >> 5;   // 32 x 8
#pragma unroll
    for (int i = 0; i < 32; i += 8)
        tl[y + i][x] = q8(in[(r0 + y + i) * 512 + c0 + x]);
    __syncthreads();
#pragma unroll
    for (int i = 0; i < 32; i += 8)
        out[(c0 + y + i) * 512 + r0 + x] = tl[x][y + i];
}

// acc[p][i][q][j] += sum_k X[k][m0 + p*64 + tx*4 + i] * W[k][n0 + q*64 + ty*4 + j],
// k strictly ascending. X, W are [KTOT][512] row-major.
// LDS: Xs/Ws [32][128], single-buffered, BK=32 per barrier pair. Fragments are
// 16-B chunks at 4-dword stride -> 2-way bank aliasing max (free), Ws reads
// broadcast within quarter-waves.
__device__ __forceinline__ void gemm_pass(const float* __restrict__ X,
                                          const float* __restrict__ W,
                                          int m0, int n0, int KTOT,
                                          float (&acc)[2][4][2][4],
                                          float (*Xs)[128], float (*Ws)[128],
                                          int tid) {
    const int tx = tid & 15, ty = tid >> 4;
    const int srow = tid >> 4, sseg4 = (tid & 15) * 4;   // 16 rows x 16 chunks
    const float* xp = X + (size_t)srow * 512 + m0 + sseg4;
    const float* wp = W + (size_t)srow * 512 + n0 + sseg4;
    for (int k0 = 0; k0 < KTOT; k0 += 32) {
        // stage rows srow and srow+16 of the 32-row tile, both halves (0/64)
        float4 x0 = *(const float4*)xp;
        float4 x1 = *(const float4*)(xp + 64);
        float4 x2 = *(const float4*)(xp + 16 * 512);
        float4 x3 = *(const float4*)(xp + 16 * 512 + 64);
        float4 w0 = *(const float4*)wp;
        float4 w1 = *(const float4*)(wp + 64);
        float4 w2 = *(const float4*)(wp + 16 * 512);
        float4 w3 = *(const float4*)(wp + 16 * 512 + 64);
        xp += 32 * 512; wp += 32 * 512;
        __syncthreads();                 // prev-tile reads done before overwrite
        *(float4*)&Xs[srow][sseg4]           = x0;
        *(float4*)&Xs[srow][64 + sseg4]      = x1;
        *(float4*)&Xs[16 + srow][sseg4]      = x2;
        *(float4*)&Xs[16 + srow][64 + sseg4] = x3;
        *(float4*)&Ws[srow][sseg4]           = w0;
        *(float4*)&Ws[srow][64 + sseg4]      = w1;
        *(float4*)&Ws[16 + srow][sseg4]      = w2;
        *(float4*)&Ws[16 + srow][64 + sseg4] = w3;
        __syncthreads();
#pragma unroll
        for (int k = 0; k < 32; ++k) {
            float a[2][4], b[2][4];
            *(float4*)&a[0][0] = *(const float4*)&Xs[k][tx * 4];
            *(float4*)&a[1][0] = *(const float4*)&Xs[k][64 + tx * 4];
            *(float4*)&b[0][0] = *(const float4*)&Ws[k][ty * 4];
            *(float4*)&b[1][0] = *(const float4*)&Ws[k][64 + ty * 4];
#pragma unroll
            for (int p = 0; p < 2; ++p)
#pragma unroll
                for (int i = 0; i < 4; ++i)
#pragma unroll
                    for (int q = 0; q < 2; ++q)
#pragma unroll
                        for (int j = 0; j < 4; ++j)
                            acc[p][i][q][j] = fmaf(a[p][i], b[q][j], acc[p][i][q][j]);
        }
    }
}

// R[b][t][n] = sum_d u[b][d][t] * Bqt[d][n]. grid (4,4,32), block 256.
__global__ __launch_bounds__(256) void gemm_R(const float* __restrict__ u,
                                              const float* __restrict__ Bqt,
                                              float* __restrict__ R) {
    __shared__ float Xs[32][128];
    __shared__ float Ws[32][128];
    const int b  = blockIdx.z;
    const int t0 = blockIdx.x * 128, n0 = blockIdx.y * 128;
    const int tid = threadIdx.x;
    const int tx = tid & 15, ty = tid >> 4;
    const float* ub = u + (size_t)b * (DINX * LSEQ);
    float acc[2][4][2][4] = {};
    gemm_pass(ub, Bqt, t0, n0, DINX, acc, Xs, Ws, tid);
    float* Rb = R + (size_t)b * (LSEQ * NDIM);
#pragma unroll
    for (int p = 0; p < 2; ++p)
#pragma unroll
        for (int i = 0; i < 4; ++i) {
            float* row = Rb + (size_t)(t0 + p * 64 + tx * 4 + i) * NDIM + n0;
            *(float4*)(row + ty * 4)      = make_float4(acc[p][i][0][0], acc[p][i][0][1],
                                                        acc[p][i][0][2], acc[p][i][0][3]);
            *(float4*)(row + 64 + ty * 4) = make_float4(acc[p][i][1][0], acc[p][i][1][1],
                                                        acc[p][i][1][2], acc[p][i][1][3]);
        }
}

// Per-(b, n-chunk) recurrence (bitwise np: mul-then-add, q8). Writes S[b][n][t].
// grid (32, 8), block 64 (thread = one n within a 64-wide chunk) -> 256 blocks,
// one chain-wave per CU.
__global__ __launch_bounds__(64) void recur(const float* __restrict__ R,
                                            const float* __restrict__ Aq,
                                            float* __restrict__ S) {
    __shared__ float tile[16][68];
    const int b  = blockIdx.x;
    const int n0 = blockIdx.y * 64;
    const int n  = threadIdx.x;                 // 0..63
    const float a = Aq[n0 + n];
    const float* Rb = R + (size_t)b * (LSEQ * NDIM) + n0;
    float* Sb = S + (size_t)b * (NDIM * LSEQ) + (size_t)n0 * LSEQ;
    float s = 0.0f;
    const int c = (n & 3) * 4;
    const int rbase = n >> 2;                   // 0..15
    for (int t0 = 0; t0 < LSEQ; t0 += 16) {
#pragma unroll
        for (int tt = 0; tt < 16; ++tt) {
            float r = Rb[(size_t)(t0 + tt) * NDIM + n];
            s = q8(__fadd_rn(__fmul_rn(s, a), r));
            tile[tt][n] = s;
        }
        __syncthreads();
#pragma unroll
        for (int p = 0; p < 4; ++p) {
            int row = p * 16 + rbase;
            float4 v = make_float4(tile[c + 0][row], tile[c + 1][row],
                                   tile[c + 2][row], tile[c + 3][row]);
            *(float4*)(Sb + (size_t)row * LSEQ + t0 + c) = v;
        }
        __syncthreads();
    }
}

// Y[b][o][t] = q8( (sum_n S[n][t]*Cqt[n][o]) + (sum_d u[d][t]*Dqt[d][o]) )
__global__ __launch_bounds__(256) void gemm_Y(const float* __restrict__ u,
                                              const float* __restrict__ S,
                                              const float* __restrict__ Cqt,
                                              const float* __restrict__ Dqt,
                                              float* __restrict__ Y) {
    __shared__ float Xs[32][128];
    __shared__ float Ws[32][128];
    const int b  = blockIdx.z;
    const int t0 = blockIdx.x * 128, o0 = blockIdx.y * 128;
    const int tid = threadIdx.x;
    const int tx = tid & 15, ty = tid >> 4;
    const float* Sb = S + (size_t)b * (NDIM * LSEQ);
    const float* ub = u + (size_t)b * (DINX * LSEQ);
    float acc[2][4][2][4] = {};
    float c1[2][4][2][4];
    gemm_pass(Sb, Cqt, t0, o0, NDIM, acc, Xs, Ws, tid);
#pragma unroll
    for (int p = 0; p < 2; ++p)
#pragma unroll
        for (int i = 0; i < 4; ++i)
#pragma unroll
            for (int q = 0; q < 2; ++q)
#pragma unroll
                for (int j = 0; j < 4; ++j) {
                    c1[p][i][q][j] = acc[p][i][q][j];
                    acc[p][i][q][j] = 0.0f;
                }
    gemm_pass(ub, Dqt, t0, o0, DINX, acc, Xs, Ws, tid);

    float* Yb = Y + (size_t)b * (NDIM * LSEQ);
#pragma unroll
    for (int q = 0; q < 2; ++q)
#pragma unroll
        for (int j = 0; j < 4; ++j) {
            float y0[4], y1[4];
#pragma unroll
            for (int i = 0; i < 4; ++i) {
                y0[i] = q8(__fadd_rn(c1[0][i][q][j], acc[0][i][q][j]));
                y1[i] = q8(__fadd_rn(c1[1][i][q][j], acc[1][i][q][j]));
            }
            float* row = Yb + (size_t)(o0 + q * 64 + ty * 4 + j) * LSEQ + t0;
            *(float4*)(row + tx * 4)      = make_float4(y0[0], y0[1], y0[2], y0[3]);
            *(float4*)(row + 64 + tx * 4) = make_float4(y1[0], y1[1], y1[2], y1[3]);
        }
}

extern "C" void kernel_launch(void* const* d_in, const int* in_sizes, int n_in,
                              void* d_out, int out_size, void* d_ws, size_t ws_size,
                              hipStream_t stream) {
    const float* u = (const float*)d_in[0];   // (32, 512, 512)
    const float* A = (const float*)d_in[1];   // (512,)
    const float* B = (const float*)d_in[2];   // (512, 512)
    const float* C = (const float*)d_in[3];   // (512, 512)
    const float* D = (const float*)d_in[4];   // (512, 512)

    float* ws  = (float*)d_ws;
    float* Aq  = ws;                    // 512
    float* Bqt = Aq + 512;              // 262144  [d][n]
    float* Cqt = Bqt + 262144;          // 262144  [n][o]
    float* Dqt = Cqt + 262144;          // 262144  [d][o]
    float* R   = Dqt + 262144;          // 8388608 [b][t][n]
    float* S   = R + 8388608;           // 8388608 [b][n][t]
    float* Y   = (float*)d_out;         // 8388608 [b][o][t]

    quantk<<<2, 256, 0, stream>>>(A, Aq, 512);
    quantT3<<<dim3(16, 16, 3), 256, 0, stream>>>(B, C, D, Bqt, Cqt, Dqt);

    gemm_R<<<dim3(4, 4, 32), 256, 0, stream>>>(u, Bqt, R);
    recur<<<dim3(32, 8), 64, 0, stream>>>(R, Aq, S);
    gemm_Y<<<dim3(4, 4, 32), 256, 0, stream>>>(u, S, Cqt, Dqt, Y);
}